// Round 11
// baseline (11173.579 us; speedup 1.0000x reference)
//
#include <hip/hip_runtime.h>
#include <hip/hip_bf16.h>
#include <stdint.h>

// BitLinear: out = x @ (sign(W)*(|W|>0.7*mean|W|)*scale)^T
// M=16384 (8*2048), K=4096, N=16384. All f32 in/out.
// Round 11: TWO blocks/CU for independent sync domains. 4-wave blocks (2x2),
// tile 128x256, per-wave 64x128, BK=32, THREE rotating LDS buffers (72 KiB ->
// 2 blocks/CU). r6/r10 MFMA<->ds_read interleave, counted vmcnt(6) (stage t+2,
// same 2-tile WAR separation as r10), no lgkm drain (compiler counted waits),
// validated 0-conflict swizzles. Cluster map: XCD owns bn-slab, 8bm x 8bn
// co-resident rectangles. Bit-identical accumulation order (absmax 2.0).
// Prep kernels byte-identical to rounds 1-10.

typedef __attribute__((ext_vector_type(8))) __bf16 bf16x8;
typedef __attribute__((ext_vector_type(4))) float f32x4;
typedef __attribute__((ext_vector_type(8))) unsigned short u16x8;

#define M_ROWS 16384
#define K_DIM  4096
#define N_DIM  16384

#define RED_BLOCKS 2048

// ---------- kernel 1a: per-block partial sums of |W| (deterministic) ----------
__global__ void absum_part_kernel(const float4* __restrict__ W4,
                                  double* __restrict__ part, long long n4) {
  double s = 0.0;
  const long long stride = (long long)gridDim.x * blockDim.x;
  for (long long i = (long long)blockIdx.x * blockDim.x + threadIdx.x; i < n4; i += stride) {
    float4 v = W4[i];
    s += (double)fabsf(v.x);
    s += (double)fabsf(v.y);
    s += (double)fabsf(v.z);
    s += (double)fabsf(v.w);
  }
  for (int o = 32; o > 0; o >>= 1) s += __shfl_down(s, o, 64);
  __shared__ double p[4];
  if ((threadIdx.x & 63) == 0) p[threadIdx.x >> 6] = s;
  __syncthreads();
  if (threadIdx.x == 0) part[blockIdx.x] = p[0] + p[1] + p[2] + p[3];
}

// ---------- kernel 1b: reduce partials -> total sum ----------
__global__ void reduce_sum_kernel(const double* __restrict__ part,
                                  double* __restrict__ sum, int n) {
  double s = 0.0;
  for (int i = threadIdx.x; i < n; i += blockDim.x) s += part[i];
  for (int o = 32; o > 0; o >>= 1) s += __shfl_down(s, o, 64);
  __shared__ double p[4];
  if ((threadIdx.x & 63) == 0) p[threadIdx.x >> 6] = s;
  __syncthreads();
  if (threadIdx.x == 0) *sum = p[0] + p[1] + p[2] + p[3];
}

// ---------- kernel 2: ternary-quantize W -> bf16 bit patterns ----------
__device__ __forceinline__ unsigned short tern_bf16(float w, float thr) {
  return (fabsf(w) > thr) ? ((w > 0.0f) ? (unsigned short)0x3F80u
                                        : (unsigned short)0xBF80u)
                          : (unsigned short)0u;
}

__global__ void quant_w_kernel(const float4* __restrict__ W4,
                               unsigned short* __restrict__ Wq,
                               const double* __restrict__ sum_ptr, long long n8) {
  const double mean = *sum_ptr / (double)((long long)N_DIM * K_DIM);
  const float thr = (float)(0.7 * mean);
  const long long stride = (long long)gridDim.x * blockDim.x;
  for (long long i = (long long)blockIdx.x * blockDim.x + threadIdx.x; i < n8; i += stride) {
    float4 a = W4[2 * i];
    float4 b = W4[2 * i + 1];
    u16x8 q;
    q[0] = tern_bf16(a.x, thr); q[1] = tern_bf16(a.y, thr);
    q[2] = tern_bf16(a.z, thr); q[3] = tern_bf16(a.w, thr);
    q[4] = tern_bf16(b.x, thr); q[5] = tern_bf16(b.y, thr);
    q[6] = tern_bf16(b.z, thr); q[7] = tern_bf16(b.w, thr);
    *(u16x8*)(Wq + i * 8) = q;
  }
}

// ---------- kernel 3: x f32 -> bf16 (RNE) ----------
__device__ __forceinline__ unsigned short f32_to_bf16_rne(float f) {
  unsigned int u = __float_as_uint(f);
  u += 0x7FFFu + ((u >> 16) & 1u);
  return (unsigned short)(u >> 16);
}

__global__ void cvt_x_kernel(const float4* __restrict__ X4,
                             unsigned short* __restrict__ Xb, long long n8) {
  const long long stride = (long long)gridDim.x * blockDim.x;
  for (long long i = (long long)blockIdx.x * blockDim.x + threadIdx.x; i < n8; i += stride) {
    float4 a = X4[2 * i];
    float4 b = X4[2 * i + 1];
    u16x8 q;
    q[0] = f32_to_bf16_rne(a.x); q[1] = f32_to_bf16_rne(a.y);
    q[2] = f32_to_bf16_rne(a.z); q[3] = f32_to_bf16_rne(a.w);
    q[4] = f32_to_bf16_rne(b.x); q[5] = f32_to_bf16_rne(b.y);
    q[6] = f32_to_bf16_rne(b.z); q[7] = f32_to_bf16_rne(b.w);
    *(u16x8*)(Xb + i * 8) = q;
  }
}

// ---------- kernel 4: bf16 GEMM, 128x256 tile, 4 waves, 3-buffer, 2 blk/CU ----------
#define BM 128
#define BN 256
#define BK 32
#define NT (K_DIM / BK)   // 128

__global__ __launch_bounds__(256, 2) void gemm_bt_kernel(
    const unsigned short* __restrict__ A,   // [M][K] bf16 bits
    const unsigned short* __restrict__ B,   // [N][K] bf16 bits (ternary)
    float* __restrict__ C,                  // [M][N] f32
    const float* __restrict__ scale_ptr) {
  constexpr int K = K_DIM, N = N_DIM;
  // 3 rotating buffers: A 3x128x32, B 3x256x32 (72 KiB total)
  __shared__ __align__(16) unsigned short Alds[3][BM][BK];
  __shared__ __align__(16) unsigned short Blds[3][BN][BK];

  const int tid = threadIdx.x;
  const int wave = tid >> 6;      // 0..3
  const int lane = tid & 63;

  // Clustered XCD map: XCD x owns bn in [8x,8x+8); co-resident batches of 64
  // blocks form 8bm x 8bn rectangles (A 8-way, B 8-way L2 sharing).
  const int x = blockIdx.x & 7;    // XCD
  const int l = blockIdx.x >> 3;   // 0..1023 within XCD
  const int g = l >> 6;            // round 0..15
  const int s = l & 63;            // position in 8x8 rectangle
  const int bm = g * 8 + (s & 7);  // 0..127
  const int bn = x * 8 + (s >> 3); // 0..63

  const int wr = wave >> 1;        // 0..1: 64 A rows each
  const int wc = wave & 1;         // 0..1: 128 B rows each

  const unsigned short* Ag = A + (size_t)(bm * BM) * K;
  const unsigned short* Bg = B + (size_t)(bn * BN) * K;

  // staging: chunk = 16 rows x 64B; LDS dest linear; bank swizzle applied
  // inverse at the global source (rule 21), constants validated r4-r10.
  const int strow = lane >> 2;                               // row in chunk 0..15
  const int scol = ((((lane & 3) - (lane >> 3)) & 3) << 3);  // src col in shorts

  // fragment read (validated 0 conflicts): row = base16 + (lane&15);
  // slot' = ((lane>>4) + (row>>1)) & 3   (valid for any 16-aligned base)
  const int frow = lane & 15;
  const int fsw = ((((lane >> 4) + ((lane & 15) >> 1)) & 3) << 3);  // shorts

  // 24 staging chunks/tile: 0..7 = A rows c*16.., 8..23 = B rows (c-8)*16..
  // wave w stages chunks [6w, 6w+6) -> 6 gload_lds per wave per tile.
#define STAGE(u, bi)                                                                 \
  {                                                                                  \
    const int kk0_ = (u) * BK;                                                       \
    _Pragma("unroll")                                                                \
    for (int i_ = 0; i_ < 6; ++i_) {                                                 \
      const int c_ = wave * 6 + i_;                                                  \
      if (c_ < 8) {                                                                  \
        const int row_ = c_ * 16 + strow;                                            \
        __builtin_amdgcn_global_load_lds(                                            \
            (__attribute__((address_space(1))) void*)(Ag + (size_t)row_ * K + kk0_ + scol), \
            (__attribute__((address_space(3))) void*)(&Alds[bi][c_ * 16][0]), 16, 0, 0); \
      } else {                                                                       \
        const int cb_ = c_ - 8;                                                      \
        const int row_ = cb_ * 16 + strow;                                           \
        __builtin_amdgcn_global_load_lds(                                            \
            (__attribute__((address_space(1))) void*)(Bg + (size_t)row_ * K + kk0_ + scol), \
            (__attribute__((address_space(3))) void*)(&Blds[bi][cb_ * 16][0]), 16, 0, 0); \
      }                                                                              \
    }                                                                                \
  }

#define RD_A(bi, m_) \
  (*(const bf16x8*)(&Alds[bi][wr * 64 + (m_) * 16 + frow][0] + fsw))
#define RD_B(bi, n_) \
  (*(const bf16x8*)(&Blds[bi][wc * 128 + (n_) * 16 + frow][0] + fsw))

#define MF4(m_, nq_, CA, CB)                                                         \
  {                                                                                  \
    _Pragma("unroll")                                                                \
    for (int n_ = (nq_) * 4; n_ < (nq_) * 4 + 4; ++n_)                               \
      acc[m_][n_] = __builtin_amdgcn_mfma_f32_16x16x32_bf16(CA[m_], CB[n_],          \
                                                            acc[m_][n_], 0, 0, 0);   \
  }

#define SB __builtin_amdgcn_sched_barrier(0)

  // iter: STAGE(t+2, SBUF) -> counted vmcnt(6) -> barrier -> 8 MFMA groups with
  // frags(t+1) reads (from NBUF) threaded between groups. No lgkm drain: the
  // compiler emits exact counted lgkmcnt before each consuming MFMA.
#define ITER(T, CA, CB, NA, NB, RD, SBUF, NBUF)                                      \
  {                                                                                  \
    if ((T) + 2 < NT) STAGE((T) + 2, SBUF);                                          \
    SB;                                                                              \
    if ((T) < NT - 2) {                                                              \
      asm volatile("s_waitcnt vmcnt(6)" ::: "memory");                               \
    } else if ((T) == NT - 2) {                                                      \
      asm volatile("s_waitcnt vmcnt(0)" ::: "memory");                               \
    }                                                                                \
    __builtin_amdgcn_s_barrier();                                                    \
    SB;                                                                              \
    __builtin_amdgcn_s_setprio(1);                                                   \
    MF4(0, 0, CA, CB);                                                               \
    SB;                                                                              \
    if (RD) { NB[0] = RD_B(NBUF, 0); NB[1] = RD_B(NBUF, 1); }                        \
    SB;                                                                              \
    MF4(0, 1, CA, CB);                                                               \
    SB;                                                                              \
    if (RD) { NB[2] = RD_B(NBUF, 2); NB[3] = RD_B(NBUF, 3); }                        \
    SB;                                                                              \
    MF4(1, 0, CA, CB);                                                               \
    SB;                                                                              \
    if (RD) { NB[4] = RD_B(NBUF, 4); NB[5] = RD_B(NBUF, 5); }                        \
    SB;                                                                              \
    MF4(1, 1, CA, CB);                                                               \
    SB;                                                                              \
    if (RD) { NB[6] = RD_B(NBUF, 6); NB[7] = RD_B(NBUF, 7); }                        \
    SB;                                                                              \
    MF4(2, 0, CA, CB);                                                               \
    SB;                                                                              \
    if (RD) { NA[0] = RD_A(NBUF, 0); NA[1] = RD_A(NBUF, 1); }                        \
    SB;                                                                              \
    MF4(2, 1, CA, CB);                                                               \
    SB;                                                                              \
    if (RD) { NA[2] = RD_A(NBUF, 2); NA[3] = RD_A(NBUF, 3); }                        \
    SB;                                                                              \
    MF4(3, 0, CA, CB);                                                               \
    MF4(3, 1, CA, CB);                                                               \
    __builtin_amdgcn_s_setprio(0);                                                   \
    SB;                                                                              \
  }

  f32x4 acc[4][8] = {};
  bf16x8 af0[4], bf0[8], af1[4], bf1[8];

  // ---------- prologue: stage tiles 0,1 (12 loads/wave); read frags(0) ----------
  STAGE(0, 0);
  STAGE(1, 1);
  asm volatile("s_waitcnt vmcnt(6)" ::: "memory");  // tile 0 landed; 1 in flight
  __builtin_amdgcn_s_barrier();
  SB;
#pragma unroll
  for (int n = 0; n < 8; ++n) bf0[n] = RD_B(0, n);
#pragma unroll
  for (int m = 0; m < 4; ++m) af0[m] = RD_A(0, m);
  SB;

  // period-6 unroll (buffers mod 3, frag sets mod 2); 126 = 6*21
  for (int t = 0; t < NT - 2; t += 6) {
    ITER(t + 0, af0, bf0, af1, bf1, 1, 2, 1);
    ITER(t + 1, af1, bf1, af0, bf0, 1, 0, 2);
    ITER(t + 2, af0, bf0, af1, bf1, 1, 1, 0);
    ITER(t + 3, af1, bf1, af0, bf0, 1, 2, 1);
    ITER(t + 4, af0, bf0, af1, bf1, 1, 0, 2);
    ITER(t + 5, af1, bf1, af0, bf0, 1, 1, 0);
  }
  ITER(NT - 2, af0, bf0, af1, bf1, 1, 2, 1);   // t=126: buf0 current, reads buf1
  ITER(NT - 1, af1, bf1, af0, bf0, 0, 0, 2);   // t=127: no further reads/stages
#undef ITER
#undef SB
#undef MF4
#undef RD_A
#undef RD_B
#undef STAGE

  // ---------------- epilogue ----------------
  const float scale = *scale_ptr;
  const int crow0 = bm * BM + wr * 64;
  const int ccol0 = bn * BN + wc * 128;
#pragma unroll
  for (int m = 0; m < 4; ++m)
#pragma unroll
    for (int n = 0; n < 8; ++n)
#pragma unroll
      for (int j = 0; j < 4; ++j) {
        // C/D layout (m89-verified): col = lane&15, row = (lane>>4)*4 + j
        const int row = crow0 + m * 16 + ((lane >> 4) << 2) + j;
        const int col = ccol0 + n * 16 + (lane & 15);
        C[(size_t)row * N + col] = acc[m][n][j] * scale;
      }
}

extern "C" void kernel_launch(void* const* d_in, const int* in_sizes, int n_in,
                              void* d_out, int out_size, void* d_ws, size_t ws_size,
                              hipStream_t stream) {
  (void)in_sizes; (void)n_in; (void)out_size; (void)ws_size;
  const float* x = (const float*)d_in[0];
  const float* w = (const float*)d_in[1];
  const float* scale = (const float*)d_in[2];
  float* out = (float*)d_out;

  char* ws = (char*)d_ws;
  double* part = (double*)ws;
  double* sum = (double*)(ws + 16384);
  unsigned short* Wq = (unsigned short*)(ws + 32768);
  unsigned short* Xb = (unsigned short*)(ws + 32768 + (size_t)N_DIM * K_DIM * 2);

  const long long nW = (long long)N_DIM * K_DIM;   // 67108864
  const long long nX = (long long)M_ROWS * K_DIM;  // 67108864

  absum_part_kernel<<<RED_BLOCKS, 256, 0, stream>>>((const float4*)w, part, nW / 4);
  reduce_sum_kernel<<<1, 256, 0, stream>>>(part, sum, RED_BLOCKS);
  quant_w_kernel<<<2048, 256, 0, stream>>>((const float4*)w, Wq, sum, nW / 8);
  cvt_x_kernel<<<2048, 256, 0, stream>>>((const float4*)x, Xb, nX / 8);

  const int nblocks = (M_ROWS / BM) * (N_DIM / BN);  // 8192
  gemm_bt_kernel<<<nblocks, 256, 0, stream>>>(Xb, Wq, out, scale);
}

// Round 12
// 2129.618 us; speedup vs baseline: 5.2468x; 5.2468x over previous
//
#include <hip/hip_runtime.h>
#include <hip/hip_bf16.h>
#include <stdint.h>

// BitLinear: out = x @ (sign(W)*(|W|>0.7*mean|W|)*scale)^T
// M=16384 (8*2048), K=4096, N=16384. All f32 in/out.
// Round 12: r10 base (champion) with B moved OFF LDS. Wq stored K-blocked
// [K/8][N][8] so B fragments load global->reg fully coalesced (256B bursts)
// from the L2-resident panel. LDS holds A only (4 x 16KB rotating buffers):
// LDS pipe 80KB/tile < matrix pipe -> matrix-bound. FIFO-exact counted vmcnt
// (12 steady / 10 / 8 tail). r6/r10 MFMA<->ds_read interleave for A, validated
// 0-conflict swizzles, r7 cluster map. Bit-identical accumulation (absmax 2.0).

typedef __attribute__((ext_vector_type(8))) __bf16 bf16x8;
typedef __attribute__((ext_vector_type(4))) float f32x4;
typedef __attribute__((ext_vector_type(8))) unsigned short u16x8;

#define M_ROWS 16384
#define K_DIM  4096
#define N_DIM  16384

#define RED_BLOCKS 2048

// ---------- kernel 1a: per-block partial sums of |W| (deterministic) ----------
__global__ void absum_part_kernel(const float4* __restrict__ W4,
                                  double* __restrict__ part, long long n4) {
  double s = 0.0;
  const long long stride = (long long)gridDim.x * blockDim.x;
  for (long long i = (long long)blockIdx.x * blockDim.x + threadIdx.x; i < n4; i += stride) {
    float4 v = W4[i];
    s += (double)fabsf(v.x);
    s += (double)fabsf(v.y);
    s += (double)fabsf(v.z);
    s += (double)fabsf(v.w);
  }
  for (int o = 32; o > 0; o >>= 1) s += __shfl_down(s, o, 64);
  __shared__ double p[4];
  if ((threadIdx.x & 63) == 0) p[threadIdx.x >> 6] = s;
  __syncthreads();
  if (threadIdx.x == 0) part[blockIdx.x] = p[0] + p[1] + p[2] + p[3];
}

// ---------- kernel 1b: reduce partials -> total sum ----------
__global__ void reduce_sum_kernel(const double* __restrict__ part,
                                  double* __restrict__ sum, int n) {
  double s = 0.0;
  for (int i = threadIdx.x; i < n; i += blockDim.x) s += part[i];
  for (int o = 32; o > 0; o >>= 1) s += __shfl_down(s, o, 64);
  __shared__ double p[4];
  if ((threadIdx.x & 63) == 0) p[threadIdx.x >> 6] = s;
  __syncthreads();
  if (threadIdx.x == 0) *sum = p[0] + p[1] + p[2] + p[3];
}

// ---------- kernel 2: ternary-quantize W -> K-blocked bf16 [K/8][N][8] ----------
__device__ __forceinline__ unsigned short tern_bf16(float w, float thr) {
  return (fabsf(w) > thr) ? ((w > 0.0f) ? (unsigned short)0x3F80u
                                        : (unsigned short)0xBF80u)
                          : (unsigned short)0u;
}

__global__ void quant_w_kernel(const float* __restrict__ W,
                               unsigned short* __restrict__ Wqb,
                               const double* __restrict__ sum_ptr, long long nblk) {
  const double mean = *sum_ptr / (double)((long long)N_DIM * K_DIM);
  const float thr = (float)(0.7 * mean);
  const long long stride = (long long)gridDim.x * blockDim.x;
  for (long long i = (long long)blockIdx.x * blockDim.x + threadIdx.x; i < nblk; i += stride) {
    const int n = (int)(i & (N_DIM - 1));      // N = 16384 = 2^14
    const int kb = (int)(i >> 14);             // 0..K/8-1
    const float* src = W + (size_t)n * K_DIM + kb * 8;
    float4 a = *(const float4*)(src);
    float4 b = *(const float4*)(src + 4);
    u16x8 q;
    q[0] = tern_bf16(a.x, thr); q[1] = tern_bf16(a.y, thr);
    q[2] = tern_bf16(a.z, thr); q[3] = tern_bf16(a.w, thr);
    q[4] = tern_bf16(b.x, thr); q[5] = tern_bf16(b.y, thr);
    q[6] = tern_bf16(b.z, thr); q[7] = tern_bf16(b.w, thr);
    *(u16x8*)(Wqb + i * 8) = q;               // coalesced: i*16B contiguous
  }
}

// ---------- kernel 3: x f32 -> bf16 (RNE) ----------
__device__ __forceinline__ unsigned short f32_to_bf16_rne(float f) {
  unsigned int u = __float_as_uint(f);
  u += 0x7FFFu + ((u >> 16) & 1u);
  return (unsigned short)(u >> 16);
}

__global__ void cvt_x_kernel(const float4* __restrict__ X4,
                             unsigned short* __restrict__ Xb, long long n8) {
  const long long stride = (long long)gridDim.x * blockDim.x;
  for (long long i = (long long)blockIdx.x * blockDim.x + threadIdx.x; i < n8; i += stride) {
    float4 a = X4[2 * i];
    float4 b = X4[2 * i + 1];
    u16x8 q;
    q[0] = f32_to_bf16_rne(a.x); q[1] = f32_to_bf16_rne(a.y);
    q[2] = f32_to_bf16_rne(a.z); q[3] = f32_to_bf16_rne(a.w);
    q[4] = f32_to_bf16_rne(b.x); q[5] = f32_to_bf16_rne(b.y);
    q[6] = f32_to_bf16_rne(b.z); q[7] = f32_to_bf16_rne(b.w);
    *(u16x8*)(Xb + i * 8) = q;
  }
}

// ---------- kernel 4: bf16 GEMM, 256x256, BK=32, A-LDS / B-global-blocked ----------
#define BM 256
#define BN 256
#define BK 32
#define NT (K_DIM / BK)   // 128

__global__ __launch_bounds__(512, 2) void gemm_bt_kernel(
    const unsigned short* __restrict__ A,    // [M][K] bf16 bits
    const unsigned short* __restrict__ Bq,   // [K/8][N][8] bf16 bits (ternary)
    float* __restrict__ C,                   // [M][N] f32
    const float* __restrict__ scale_ptr) {
  constexpr int K = K_DIM, N = N_DIM;
  // 4 rotating A buffers x 256 rows x 32 shorts = 64 KiB
  __shared__ __align__(16) unsigned short Alds[4][BM][BK];

  const int tid = threadIdx.x;
  const int wave = tid >> 6;      // 0..7
  const int lane = tid & 63;

  // 2D-clustered XCD map (r7-validated: FETCH ~1.57GB)
  const int x = blockIdx.x & 7;   // XCD
  const int l = blockIdx.x >> 3;  // 0..511 within XCD
  const int g = l >> 5;           // round 0..15
  const int s = l & 31;           // position in 4x8 rectangle
  const int bm = g * 4 + (s & 3); // 0..63
  const int bn = x * 8 + (s >> 2);// 0..63

  const int wr = wave >> 2;       // 0..1  (128 A rows each)
  const int wc = wave & 3;        // 0..3  (64 B cols each)

  const unsigned short* Ag = A + (size_t)(bm * BM) * K;
  // B fragment base (blocked layout): element (kb, col) at (kb*N + col)*8.
  // Per lane: col = bn*256 + wc*64 + n*16 + (lane&15); kb = t*4 + (lane>>4).
  const unsigned short* Bw =
      Bq + ((size_t)(lane >> 4) * N + bn * BN + wc * 64 + (lane & 15)) * 8;

  // A staging: chunk = 16 rows x 64B; LDS dest linear; bank swizzle applied
  // inverse at the global source (rule 21), constants validated r4-r10.
  const int strow = lane >> 2;                               // row in chunk 0..15
  const int scol = ((((lane & 3) - (lane >> 3)) & 3) << 3);  // src col in shorts

  // A fragment read (validated 0 conflicts): row = base16 + (lane&15);
  // slot' = ((lane>>4) + (row>>1)) & 3
  const int frow = lane & 15;
  const int fsw = ((((lane >> 4) + ((lane & 15) >> 1)) & 3) << 3);  // shorts

  // 16 A chunks/tile; wave stages chunks 2w, 2w+1 -> 2 gload_lds per wave.
#define STAGE_A(u)                                                                   \
  {                                                                                  \
    _Pragma("unroll")                                                                \
    for (int i_ = 0; i_ < 2; ++i_) {                                                 \
      const int ch_ = wave * 2 + i_;                                                 \
      const int row_ = ch_ * 16 + strow;                                             \
      __builtin_amdgcn_global_load_lds(                                              \
          (__attribute__((address_space(1))) void*)(Ag + (size_t)row_ * K + (u) * BK + scol), \
          (__attribute__((address_space(3))) void*)(&Alds[(u) & 3][ch_ * 16][0]), 16, 0, 0); \
    }                                                                                \
  }

#define LOADB(u, BF)                                                                 \
  {                                                                                  \
    _Pragma("unroll")                                                                \
    for (int n_ = 0; n_ < 4; ++n_)                                                   \
      BF[n_] = *(const bf16x8*)(Bw + ((size_t)(u) * 4 * N + n_ * 16) * 8);           \
  }

#define RD_A(bi, m_) \
  (*(const bf16x8*)(&Alds[bi][wr * 128 + (m_) * 16 + frow][0] + fsw))

#define MF4(m_, CA, CB)                                                              \
  {                                                                                  \
    _Pragma("unroll")                                                                \
    for (int n_ = 0; n_ < 4; ++n_)                                                   \
      acc[m_][n_] = __builtin_amdgcn_mfma_f32_16x16x32_bf16(CA[m_], CB[n_],          \
                                                            acc[m_][n_], 0, 0, 0);   \
  }

#define SB __builtin_amdgcn_sched_barrier(0)

  // iter: LOADB(t+1)->regs, STAGE_A(t+3)->LDS; counted vmcnt retires exactly
  // A(t+1) DMA (FIFO: keep A(t+2),A(t+3),B(t+1)=12 in flight); barrier; MFMA
  // cluster with A(t+1) ds_reads threaded between groups. No lgkm drain
  // (compiler counted waits); B register deps compiler-managed.
#define ITER(T, CA, CB, NA, NB, RD)                                                  \
  {                                                                                  \
    if (RD) LOADB((T) + 1, NB);                                                      \
    if ((T) + 3 < NT) STAGE_A((T) + 3);                                              \
    SB;                                                                              \
    if ((T) < NT - 3) {                                                              \
      asm volatile("s_waitcnt vmcnt(12)" ::: "memory");                              \
    } else if ((T) == NT - 3) {                                                      \
      asm volatile("s_waitcnt vmcnt(10)" ::: "memory");                              \
    } else if ((T) == NT - 2) {                                                      \
      asm volatile("s_waitcnt vmcnt(8)" ::: "memory");                               \
    }                                                                                \
    __builtin_amdgcn_s_barrier();                                                    \
    SB;                                                                              \
    __builtin_amdgcn_s_setprio(1);                                                   \
    MF4(0, CA, CB);                                                                  \
    SB;                                                                              \
    if (RD) { NA[0] = RD_A(((T) + 1) & 3, 0); NA[1] = RD_A(((T) + 1) & 3, 1); }      \
    SB;                                                                              \
    MF4(1, CA, CB);                                                                  \
    SB;                                                                              \
    if (RD) { NA[2] = RD_A(((T) + 1) & 3, 2); NA[3] = RD_A(((T) + 1) & 3, 3); }      \
    SB;                                                                              \
    MF4(2, CA, CB);                                                                  \
    SB;                                                                              \
    if (RD) { NA[4] = RD_A(((T) + 1) & 3, 4); NA[5] = RD_A(((T) + 1) & 3, 5); }      \
    SB;                                                                              \
    MF4(3, CA, CB);                                                                  \
    SB;                                                                              \
    if (RD) { NA[6] = RD_A(((T) + 1) & 3, 6); NA[7] = RD_A(((T) + 1) & 3, 7); }      \
    SB;                                                                              \
    MF4(4, CA, CB);                                                                  \
    MF4(5, CA, CB);                                                                  \
    MF4(6, CA, CB);                                                                  \
    MF4(7, CA, CB);                                                                  \
    __builtin_amdgcn_s_setprio(0);                                                   \
    SB;                                                                              \
  }

  f32x4 acc[8][4] = {};
  bf16x8 af0[8], bf0[4], af1[8], bf1[4];

  // ---------- prologue: stage A(0,1,2) [6 DMA], load B(0) [4]; wait A(0) ----------
  STAGE_A(0);
  STAGE_A(1);
  STAGE_A(2);
  LOADB(0, bf0);
  asm volatile("s_waitcnt vmcnt(8)" ::: "memory");  // A(0) landed; A(1,2),B(0) in flight
  __builtin_amdgcn_s_barrier();
  SB;
#pragma unroll
  for (int m = 0; m < 8; ++m) af0[m] = RD_A(0, m);
  SB;

  for (int t = 0; t < NT - 2; t += 2) {
    ITER(t, af0, bf0, af1, bf1, 1);
    ITER(t + 1, af1, bf1, af0, bf0, 1);
  }
  ITER(NT - 2, af0, bf0, af1, bf1, 1);   // t = 126: current set0, reads t=127
  ITER(NT - 1, af1, bf1, af0, bf0, 0);   // t = 127: no further loads/reads
#undef ITER
#undef SB
#undef MF4
#undef RD_A
#undef LOADB
#undef STAGE_A

  // ---------------- epilogue ----------------
  const float scale = *scale_ptr;
  const int crow0 = bm * BM + wr * 128;
  const int ccol0 = bn * BN + wc * 64;
#pragma unroll
  for (int m = 0; m < 8; ++m)
#pragma unroll
    for (int n = 0; n < 4; ++n)
#pragma unroll
      for (int j = 0; j < 4; ++j) {
        // C/D layout (m89-verified): col = lane&15, row = (lane>>4)*4 + j
        const int row = crow0 + m * 16 + ((lane >> 4) << 2) + j;
        const int col = ccol0 + n * 16 + (lane & 15);
        C[(size_t)row * N + col] = acc[m][n][j] * scale;
      }
}

extern "C" void kernel_launch(void* const* d_in, const int* in_sizes, int n_in,
                              void* d_out, int out_size, void* d_ws, size_t ws_size,
                              hipStream_t stream) {
  (void)in_sizes; (void)n_in; (void)out_size; (void)ws_size;
  const float* x = (const float*)d_in[0];
  const float* w = (const float*)d_in[1];
  const float* scale = (const float*)d_in[2];
  float* out = (float*)d_out;

  char* ws = (char*)d_ws;
  double* part = (double*)ws;
  double* sum = (double*)(ws + 16384);
  unsigned short* Wqb = (unsigned short*)(ws + 32768);
  unsigned short* Xb = (unsigned short*)(ws + 32768 + (size_t)N_DIM * K_DIM * 2);

  const long long nW = (long long)N_DIM * K_DIM;   // 67108864
  const long long nX = (long long)M_ROWS * K_DIM;  // 67108864

  absum_part_kernel<<<RED_BLOCKS, 256, 0, stream>>>((const float4*)w, part, nW / 4);
  reduce_sum_kernel<<<1, 256, 0, stream>>>(part, sum, RED_BLOCKS);
  quant_w_kernel<<<2048, 256, 0, stream>>>(w, Wqb, sum, nW / 8);
  cvt_x_kernel<<<2048, 256, 0, stream>>>((const float4*)x, Xb, nX / 8);

  const int nblocks = (M_ROWS / BM) * (N_DIM / BN);  // 4096
  gemm_bt_kernel<<<nblocks, 512, 0, stream>>>(Xb, Wqb, out, scale);
}

// Round 13
// 1221.456 us; speedup vs baseline: 9.1478x; 1.7435x over previous
//
#include <hip/hip_runtime.h>
#include <hip/hip_bf16.h>
#include <stdint.h>

// BitLinear: out = x @ (sign(W)*(|W|>0.7*mean|W|)*scale)^T
// M=16384 (8*2048), K=4096, N=16384. All f32 in/out.
// Round 13: i8 MFMA path. W ternary is EXACT in i8; x quantized per-row
// (symmetric, RNE, scale=rowmax/127). mfma_i32_16x16x64_i8 at ~1.9x bf16 rate,
// integer accumulation (exact, deterministic). GEMM structure = r10 champion,
// byte-identical staging/swizzle geometry (rows 64B in both), counted vmcnt(8),
// MFMA<->ds_read interleave, no lgkm drain, r7 cluster map.
// out[m][n] = float(acc_i32) * xs[m] * weight_scale.

typedef __attribute__((ext_vector_type(4))) int i32x4;
typedef __attribute__((ext_vector_type(8))) unsigned short u16x8;

#define M_ROWS 16384
#define K_DIM  4096
#define N_DIM  16384

#define RED_BLOCKS 2048

// ---------- kernel 1a: per-block partial sums of |W| (deterministic) ----------
__global__ void absum_part_kernel(const float4* __restrict__ W4,
                                  double* __restrict__ part, long long n4) {
  double s = 0.0;
  const long long stride = (long long)gridDim.x * blockDim.x;
  for (long long i = (long long)blockIdx.x * blockDim.x + threadIdx.x; i < n4; i += stride) {
    float4 v = W4[i];
    s += (double)fabsf(v.x);
    s += (double)fabsf(v.y);
    s += (double)fabsf(v.z);
    s += (double)fabsf(v.w);
  }
  for (int o = 32; o > 0; o >>= 1) s += __shfl_down(s, o, 64);
  __shared__ double p[4];
  if ((threadIdx.x & 63) == 0) p[threadIdx.x >> 6] = s;
  __syncthreads();
  if (threadIdx.x == 0) part[blockIdx.x] = p[0] + p[1] + p[2] + p[3];
}

// ---------- kernel 1b: reduce partials -> total sum ----------
__global__ void reduce_sum_kernel(const double* __restrict__ part,
                                  double* __restrict__ sum, int n) {
  double s = 0.0;
  for (int i = threadIdx.x; i < n; i += blockDim.x) s += part[i];
  for (int o = 32; o > 0; o >>= 1) s += __shfl_down(s, o, 64);
  __shared__ double p[4];
  if ((threadIdx.x & 63) == 0) p[threadIdx.x >> 6] = s;
  __syncthreads();
  if (threadIdx.x == 0) *sum = p[0] + p[1] + p[2] + p[3];
}

// ---------- kernel 2: ternary-quantize W -> i8 {-1,0,1} [N][K] ----------
__device__ __forceinline__ int tern_i8(float w, float thr) {
  return ((fabsf(w) > thr) ? ((w > 0.0f) ? 1 : -1) : 0) & 255;
}

__global__ void quant_w_kernel(const float4* __restrict__ W4,
                               signed char* __restrict__ Wq,
                               const double* __restrict__ sum_ptr, long long n16) {
  const double mean = *sum_ptr / (double)((long long)N_DIM * K_DIM);
  const float thr = (float)(0.7 * mean);
  const long long stride = (long long)gridDim.x * blockDim.x;
  for (long long i = (long long)blockIdx.x * blockDim.x + threadIdx.x; i < n16; i += stride) {
    float4 a = W4[4 * i], b = W4[4 * i + 1], c = W4[4 * i + 2], d = W4[4 * i + 3];
    int4 o;
    o.x = tern_i8(a.x, thr) | (tern_i8(a.y, thr) << 8) |
          (tern_i8(a.z, thr) << 16) | (tern_i8(a.w, thr) << 24);
    o.y = tern_i8(b.x, thr) | (tern_i8(b.y, thr) << 8) |
          (tern_i8(b.z, thr) << 16) | (tern_i8(b.w, thr) << 24);
    o.z = tern_i8(c.x, thr) | (tern_i8(c.y, thr) << 8) |
          (tern_i8(c.z, thr) << 16) | (tern_i8(c.w, thr) << 24);
    o.w = tern_i8(d.x, thr) | (tern_i8(d.y, thr) << 8) |
          (tern_i8(d.z, thr) << 16) | (tern_i8(d.w, thr) << 24);
    *(int4*)(Wq + i * 16) = o;
  }
}

// ---------- kernel 3: x f32 -> per-row symmetric i8 + scale ----------
__global__ void quant_x_kernel(const float4* __restrict__ X4,
                               signed char* __restrict__ Xq,
                               float* __restrict__ xs) {
  const int row = blockIdx.x;
  const int t = threadIdx.x;
  const float4* src = X4 + (size_t)row * (K_DIM / 4);
  float4 v[4];
#pragma unroll
  for (int i = 0; i < 4; ++i) v[i] = src[i * 256 + t];
  float m = 0.f;
#pragma unroll
  for (int i = 0; i < 4; ++i) {
    m = fmaxf(m, fabsf(v[i].x)); m = fmaxf(m, fabsf(v[i].y));
    m = fmaxf(m, fabsf(v[i].z)); m = fmaxf(m, fabsf(v[i].w));
  }
  for (int o = 32; o > 0; o >>= 1) m = fmaxf(m, __shfl_down(m, o, 64));
  __shared__ float p[4];
  if ((t & 63) == 0) p[t >> 6] = m;
  __syncthreads();
  const float bm = fmaxf(fmaxf(p[0], p[1]), fmaxf(p[2], p[3]));
  const float inv = (bm > 0.f) ? 127.0f / bm : 0.f;
  if (t == 0) xs[row] = (bm > 0.f) ? bm / 127.0f : 0.f;
  int* dst = (int*)(Xq + (size_t)row * K_DIM);
#pragma unroll
  for (int i = 0; i < 4; ++i) {
    const int q0 = __float2int_rn(v[i].x * inv) & 255;
    const int q1 = __float2int_rn(v[i].y * inv) & 255;
    const int q2 = __float2int_rn(v[i].z * inv) & 255;
    const int q3 = __float2int_rn(v[i].w * inv) & 255;
    dst[i * 256 + t] = q0 | (q1 << 8) | (q2 << 16) | (q3 << 24);
  }
}

// ---------- kernel 4: i8 GEMM, 256x256, BK=64B, r10 schedule ----------
#define BM 256
#define BN 256
#define BK 64
#define NT (K_DIM / BK)   // 64

__global__ __launch_bounds__(512, 2) void gemm_bt_kernel(
    const signed char* __restrict__ A,   // [M][K] i8 (quantized x)
    const signed char* __restrict__ B,   // [N][K] i8 ternary
    float* __restrict__ C,               // [M][N] f32
    const float* __restrict__ xs,        // [M] row scales
    const float* __restrict__ scale_ptr) {
  constexpr int K = K_DIM, N = N_DIM;
  // 4 rotating buffers x {A,B} x 256 rows x 64 bytes = 128 KiB
  __shared__ __align__(16) signed char lds[4][2][BM][BK];

  const int tid = threadIdx.x;
  const int wave = tid >> 6;      // 0..7
  const int lane = tid & 63;

  // 2D-clustered XCD map (r7-validated: minimal FETCH)
  const int x = blockIdx.x & 7;   // XCD
  const int l = blockIdx.x >> 3;  // 0..511 within XCD
  const int g = l >> 5;           // round 0..15
  const int s = l & 31;           // position in 4x8 rectangle
  const int bm = g * 4 + (s & 3); // 0..63
  const int bn = x * 8 + (s >> 2);// 0..63

  const int wr = wave >> 2;       // 0..1  (128 rows each)
  const int wc = wave & 3;        // 0..3  (64 cols each)

  const signed char* Ag = A + (size_t)(bm * BM) * K;
  const signed char* Bg = B + (size_t)(bn * BN) * K;

  // staging: chunk = 16 rows x 64B; LDS dest linear; bank swizzle applied
  // inverse at the global source (rule 21). Byte-identical geometry to r10
  // (rows are 64B in both bf16/BK32 and i8/BK64).
  const int strow = lane >> 2;                               // row in chunk 0..15
  const int scol = ((((lane & 3) - (lane >> 3)) & 3) << 4);  // src col in BYTES

  // fragment read (validated 0 conflicts): row = base16 + (lane&15);
  // 16B slot' = ((lane>>4) + (row>>1)) & 3
  const int frow = lane & 15;
  const int fsw = ((((lane >> 4) + ((lane & 15) >> 1)) & 3) << 4);  // bytes

#define STAGE(u)                                                                     \
  {                                                                                  \
    const int kk0_ = (u) * BK;                                                       \
    signed char* Ab_ = &lds[(u) & 3][0][0][0];                                       \
    signed char* Bb_ = &lds[(u) & 3][1][0][0];                                       \
    _Pragma("unroll")                                                                \
    for (int i_ = 0; i_ < 2; ++i_) {                                                 \
      const int ch_ = wave * 2 + i_;                                                 \
      const int row_ = ch_ * 16 + strow;                                             \
      __builtin_amdgcn_global_load_lds(                                              \
          (__attribute__((address_space(1))) void*)(Ag + (size_t)row_ * K + kk0_ + scol), \
          (__attribute__((address_space(3))) void*)(Ab_ + ch_ * 16 * BK), 16, 0, 0); \
      __builtin_amdgcn_global_load_lds(                                              \
          (__attribute__((address_space(1))) void*)(Bg + (size_t)row_ * K + kk0_ + scol), \
          (__attribute__((address_space(3))) void*)(Bb_ + ch_ * 16 * BK), 16, 0, 0); \
    }                                                                                \
  }

#define RD_B(P, n_) (*(const i32x4*)((P) + (wc * 64 + (n_) * 16 + frow) * BK + fsw))
#define RD_A(P, m_) (*(const i32x4*)((P) + (wr * 128 + (m_) * 16 + frow) * BK + fsw))

#define MF4(m_, CA, CB)                                                              \
  {                                                                                  \
    _Pragma("unroll")                                                                \
    for (int n_ = 0; n_ < 4; ++n_)                                                   \
      acc[m_][n_] = __builtin_amdgcn_mfma_i32_16x16x64_i8(CA[m_], CB[n_],            \
                                                          acc[m_][n_], 0, 0, 0);     \
  }

#define SB __builtin_amdgcn_sched_barrier(0)

  // iter: STAGE(t+3) -> counted vmcnt -> barrier -> MFMA cluster with frags(t+1)
  // reads threaded between groups. No lgkm drain at entry (compiler emits exact
  // counted lgkmcnt per consuming MFMA).
#define ITER(T, CA, CB, NA, NB, RD)                                                  \
  {                                                                                  \
    if ((T) + 3 < NT) STAGE((T) + 3);                                                \
    SB;                                                                              \
    if ((T) < NT - 3) {                                                              \
      asm volatile("s_waitcnt vmcnt(8)" ::: "memory");                               \
    } else if ((T) == NT - 3) {                                                      \
      asm volatile("s_waitcnt vmcnt(4)" ::: "memory");                               \
    } else if ((T) == NT - 2) {                                                      \
      asm volatile("s_waitcnt vmcnt(0)" ::: "memory");                               \
    }                                                                                \
    __builtin_amdgcn_s_barrier();                                                    \
    SB;                                                                              \
    const signed char* NAp_ = &lds[((T) + 1) & 3][0][0][0];                          \
    const signed char* NBp_ = &lds[((T) + 1) & 3][1][0][0];                          \
    __builtin_amdgcn_s_setprio(1);                                                   \
    MF4(0, CA, CB);                                                                  \
    SB;                                                                              \
    if (RD) { NB[0] = RD_B(NBp_, 0); NB[1] = RD_B(NBp_, 1); }                        \
    SB;                                                                              \
    MF4(1, CA, CB);                                                                  \
    SB;                                                                              \
    if (RD) { NB[2] = RD_B(NBp_, 2); NB[3] = RD_B(NBp_, 3); }                        \
    SB;                                                                              \
    MF4(2, CA, CB);                                                                  \
    SB;                                                                              \
    if (RD) { NA[0] = RD_A(NAp_, 0); NA[1] = RD_A(NAp_, 1); }                        \
    SB;                                                                              \
    MF4(3, CA, CB);                                                                  \
    SB;                                                                              \
    if (RD) { NA[2] = RD_A(NAp_, 2); NA[3] = RD_A(NAp_, 3); }                        \
    SB;                                                                              \
    MF4(4, CA, CB);                                                                  \
    SB;                                                                              \
    if (RD) { NA[4] = RD_A(NAp_, 4); NA[5] = RD_A(NAp_, 5); }                        \
    SB;                                                                              \
    MF4(5, CA, CB);                                                                  \
    SB;                                                                              \
    if (RD) { NA[6] = RD_A(NAp_, 6); NA[7] = RD_A(NAp_, 7); }                        \
    SB;                                                                              \
    MF4(6, CA, CB);                                                                  \
    MF4(7, CA, CB);                                                                  \
    __builtin_amdgcn_s_setprio(0);                                                   \
    SB;                                                                              \
  }

  i32x4 acc[8][4] = {};
  i32x4 af0[8], bf0[4], af1[8], bf1[4];

  // ---------- prologue: stage 0,1,2; read frags(0) into set0 ----------
  STAGE(0);
  STAGE(1);
  STAGE(2);
  asm volatile("s_waitcnt vmcnt(8)" ::: "memory");  // tile 0 landed; 1,2 in flight
  __builtin_amdgcn_s_barrier();
  SB;
#pragma unroll
  for (int n = 0; n < 4; ++n) bf0[n] = RD_B(&lds[0][1][0][0], n);
#pragma unroll
  for (int m = 0; m < 8; ++m) af0[m] = RD_A(&lds[0][0][0][0], m);
  SB;

  for (int t = 0; t < NT - 2; t += 2) {
    ITER(t, af0, bf0, af1, bf1, 1);
    ITER(t + 1, af1, bf1, af0, bf0, 1);
  }
  ITER(NT - 2, af0, bf0, af1, bf1, 1);   // t = 62 (even): current set0
  ITER(NT - 1, af1, bf1, af0, bf0, 0);   // t = 63: no further reads
#undef ITER
#undef SB
#undef MF4
#undef RD_A
#undef RD_B
#undef STAGE

  // ---------------- epilogue: dequantize ----------------
  const float wscale = *scale_ptr;
  const int crow0 = bm * BM + wr * 128;
  const int ccol0 = bn * BN + wc * 64;
#pragma unroll
  for (int m = 0; m < 8; ++m)
#pragma unroll
    for (int j = 0; j < 4; ++j) {
      // C/D layout (m89-verified, dtype-independent): col=lane&15, row=(lane>>4)*4+j
      const int row = crow0 + m * 16 + ((lane >> 4) << 2) + j;
      const float sc = xs[row] * wscale;  // quarter-wave-uniform -> broadcast load
#pragma unroll
      for (int n = 0; n < 4; ++n) {
        const int col = ccol0 + n * 16 + (lane & 15);
        C[(size_t)row * N + col] = (float)acc[m][n][j] * sc;
      }
    }
}

extern "C" void kernel_launch(void* const* d_in, const int* in_sizes, int n_in,
                              void* d_out, int out_size, void* d_ws, size_t ws_size,
                              hipStream_t stream) {
  (void)in_sizes; (void)n_in; (void)out_size; (void)ws_size;
  const float* x = (const float*)d_in[0];
  const float* w = (const float*)d_in[1];
  const float* scale = (const float*)d_in[2];
  float* out = (float*)d_out;

  // workspace: part[2048]d @0 (16KB) | sum d @16384 | xs[16384]f @32768 (64KB)
  //            Wq i8 (64MB) @98304 | Xq i8 (64MB) @98304+64MB
  char* ws = (char*)d_ws;
  double* part = (double*)ws;
  double* sum = (double*)(ws + 16384);
  float* xs = (float*)(ws + 32768);
  signed char* Wq = (signed char*)(ws + 98304);
  signed char* Xq = (signed char*)(ws + 98304 + (size_t)N_DIM * K_DIM);

  const long long nW = (long long)N_DIM * K_DIM;   // 67108864

  absum_part_kernel<<<RED_BLOCKS, 256, 0, stream>>>((const float4*)w, part, nW / 4);
  reduce_sum_kernel<<<1, 256, 0, stream>>>(part, sum, RED_BLOCKS);
  quant_w_kernel<<<2048, 256, 0, stream>>>((const float4*)w, Wq, sum, nW / 16);
  quant_x_kernel<<<M_ROWS, 256, 0, stream>>>((const float4*)x, Xq, xs);

  const int nblocks = (M_ROWS / BM) * (N_DIM / BN);  // 4096
  gemm_bt_kernel<<<nblocks, 512, 0, stream>>>(Xq, Wq, out, xs, scale);
}